// Round 14
// baseline (86.138 us; speedup 1.0000x reference)
//
#include <hip/hip_runtime.h>
#include <hip/hip_fp16.h>

#define NCELL 4096
#define CPB 4  // cells per block

typedef _Float16 f16x8 __attribute__((ext_vector_type(8)));
typedef float f32x4 __attribute__((ext_vector_type(4)));

__device__ __forceinline__ unsigned int packrn(float a, float b) {
    __half2 h = __floats2half2_rn(a, b);
    union { __half2 h; unsigned int u; } x; x.h = h; return x.u;
}

__device__ __forceinline__ int cell_of(float x0, float x1, float x2) {
    int i0 = (int)(x0 / 0.1875f + 8.0f);
    int i1 = (int)(x1 / 0.1875f + 8.0f);
    int i2 = (int)(x2 / 0.1875f + 8.0f);
    i0 = i0 < 0 ? 0 : (i0 > 15 ? 15 : i0);
    i1 = i1 < 0 ? 0 : (i1 > 15 ? 15 : i1);
    i2 = i2 < 0 ? 0 : (i2 > 15 ? 15 : i2);
    return (i0 * 16 + i1) * 16 + i2;
}

__global__ void k_count(const float* __restrict__ xs, int* __restrict__ counts,
                        float* __restrict__ out, int P) {
    int p = blockIdx.x * blockDim.x + threadIdx.x;
    if (p >= P) return;
    float x0 = xs[p * 3 + 0], x1 = xs[p * 3 + 1], x2 = xs[p * 3 + 2];
    bool m = (fabsf(x0) < 1.5f) && (fabsf(x1) < 1.5f) && (fabsf(x2) < 1.5f);
    if (m) {
        atomicAdd(&counts[cell_of(x0, x1, x2)], 1);
    } else {
        out[p * 3 + 0] = 0.0f;
        out[p * 3 + 1] = 0.0f;
        out[p * 3 + 2] = 0.0f;
        out[3 * P + p] = 0.0f;
    }
}

__global__ void k_scan(const int* __restrict__ counts, int* __restrict__ offsets,
                       int* __restrict__ cursor) {
    int l = threadIdx.x;
    const int4* c4 = (const int4*)(counts + l * 64);
    int4 v[16];
#pragma unroll
    for (int k = 0; k < 16; k++) v[k] = c4[k];
    int s = 0;
#pragma unroll
    for (int k = 0; k < 16; k++) s += v[k].x + v[k].y + v[k].z + v[k].w;
    int incl = s;
    for (int d = 1; d < 64; d <<= 1) {
        int t = __shfl_up(incl, d, 64);
        if (l >= d) incl += t;
    }
    int run = incl - s;
#pragma unroll
    for (int k = 0; k < 16; k++) {
        int4 o;
        o.x = run; run += v[k].x;
        o.y = run; run += v[k].y;
        o.z = run; run += v[k].z;
        o.w = run; run += v[k].w;
        ((int4*)(offsets + l * 64))[k] = o;
        ((int4*)(cursor + l * 64))[k] = o;
    }
    if (l == 63) offsets[4096] = run;
}

__global__ void k_scatter(const float* __restrict__ xs, int* __restrict__ cursor,
                          int* __restrict__ sorted, int P) {
    int p = blockIdx.x * blockDim.x + threadIdx.x;
    if (p >= P) return;
    float x0 = xs[p * 3 + 0], x1 = xs[p * 3 + 1], x2 = xs[p * 3 + 2];
    bool m = (fabsf(x0) < 1.5f) && (fabsf(x1) < 1.5f) && (fabsf(x2) < 1.5f);
    if (!m) return;
    int c = cell_of(x0, x1, x2);
    int pos = atomicAdd(&cursor[c], 1);
    sorted[pos] = p;
}

// ---- MFMA helpers (validated R10-R13) ----
__device__ __forceinline__ f16x8 ldB(const char* wb, int off, int blk, int lane) {
    return *(const f16x8*)(wb + off + blk * 1024 + lane * 16);
}
__device__ __forceinline__ f16x8 ldA(const char* act, int lane, int ks) {
    int p = lane & 15, g = lane >> 4;
    int byte = (p * 128 + ks * 64 + g * 16) ^ ((p & 7) << 4);
    return *(const f16x8*)(act + byte);
}
__device__ __forceinline__ void stD(char* act, int kcol, f32x4 acc, bool relu, int g4) {
#pragma unroll
    for (int r = 0; r < 4; r++) {
        int p = g4 * 4 + r;
        float v = acc[r];
        if (relu) v = fmaxf(v, 0.0f);
        *(_Float16*)(act + ((p * 128 + kcol * 2) ^ ((p & 7) << 4))) = (_Float16)v;
    }
}

// ---- split staging: phase 1 (issue loads -> regs), phase 2 (pack -> LDS) ----
// Same frag math as R11/R12's stage_fragC. BASE/j compile-time -> regs.
template <int BASE, int ITERS, int NKS>
__device__ __forceinline__ void ph1(float* va, float* vb, const float* __restrict__ W,
                                    int Krows, int Ncols, int stride, int tid) {
#pragma unroll
    for (int j = 0; j < ITERS; j++) {
        int e = tid + 256 * j;
        int m = e & 3;
        int l = (e >> 2) & 63;
        int blk = e >> 8;
        int ks = blk % NKS;
        int n = blk / NKS;
        int c = l & 15, gg = l >> 4;
        int k0 = ks * 32 + gg * 8 + 2 * m;
        int col = 16 * n + c;
        int ka = (k0 < Krows) ? k0 : (Krows - 1);
        int kb = (k0 + 1 < Krows) ? (k0 + 1) : (Krows - 1);
        int cc = (col < Ncols) ? col : (Ncols - 1);
        va[BASE + j] = W[ka * stride + cc];
        vb[BASE + j] = W[kb * stride + cc];
    }
}
template <int BASE, int ITERS>
__device__ __forceinline__ void ph2(char* wb, int off, const float* va, const float* vb,
                                    int tid) {
    unsigned int* dst = (unsigned int*)(wb + off);
#pragma unroll
    for (int j = 0; j < ITERS; j++) {
        int e = tid + 256 * j;
        int m = e & 3;
        int l = (e >> 2) & 63;
        int blk = e >> 8;
        dst[blk * 256 + l * 4 + m] = packrn(va[BASE + j], vb[BASE + j]);
    }
}

__device__ __forceinline__ void ph1_all(float* va, float* vb, float& bvv, int cell, int tid,
                                        const float* __restrict__ w1g, const float* __restrict__ b1g,
                                        const float* __restrict__ w2g, const float* __restrict__ b2g,
                                        const float* __restrict__ w3g, const float* __restrict__ b3g,
                                        const float* __restrict__ w4g, const float* __restrict__ b4g,
                                        const float* __restrict__ w5g, const float* __restrict__ b5g) {
    ph1<0, 4, 2>(va, vb, w1g + (size_t)cell * 2016, 63, 32, 32, tid);
    ph1<4, 3, 1>(va, vb, w2g + (size_t)cell * 1056, 32, 33, 33, tid);
    ph1<7, 2, 1>(va, vb, w3g + (size_t)cell * 1024, 32, 32, 32, tid);
    ph1<9, 4, 2>(va, vb, w4g + (size_t)cell * 1888, 59, 32, 32, tid);
    ph1<13, 1, 1>(va, vb, w5g + (size_t)cell * 96, 32, 3, 3, tid);
    bvv = 0.0f;
    int e = tid;
    if (e < 32) bvv = b1g[(size_t)cell * 32 + e];
    else if (e < 80) { int q = e - 32; bvv = (q < 33) ? b2g[(size_t)cell * 33 + q] : 0.0f; }
    else if (e < 112) bvv = b3g[(size_t)cell * 32 + (e - 80)];
    else if (e < 144) bvv = b4g[(size_t)cell * 32 + (e - 112)];
    else if (e < 160) { int q = e - 144; bvv = (q < 3) ? b5g[(size_t)cell * 3 + q] : 0.0f; }
}
__device__ __forceinline__ void ph2_all(char* wb, float* biasb, const float* va,
                                        const float* vb, float bvv, int tid) {
    ph2<0, 4>(wb, 0, va, vb, tid);
    ph2<4, 3>(wb, 4096, va, vb, tid);
    ph2<7, 2>(wb, 7168, va, vb, tid);
    ph2<9, 4>(wb, 9216, va, vb, tid);
    ph2<13, 1>(wb, 13312, va, vb, tid);
    if (tid < 160) biasb[tid] = bvv;
}

#define MFMA16(a, b, c) __builtin_amdgcn_mfma_f32_16x16x32_f16((a), (b), (c), 0, 0, 0)

// Validated MLP for one cell (per-wave 16-point tiles, no barriers inside).
__device__ __forceinline__ void mlp_cell(
    const char* wBc, const float* biasc, char* actA, char* actB,
    float* sigw, int* idxw, int start, int end, int wid, int lane,
    const float* __restrict__ xs, const float* __restrict__ dvs,
    const int* __restrict__ sorted, float* __restrict__ out, int P) {
    int cidx = lane & 15;
    int g4 = lane >> 4;
    for (int t0 = start + (wid << 4); t0 < end; t0 += 64) {
        int nv = end - t0; if (nv > 16) nv = 16;
        int t = t0 + cidx;
        int idx = sorted[(cidx < nv) ? t : start];
        if (g4 == 0) idxw[cidx] = idx;
        float x0 = xs[idx * 3 + 0], x1 = xs[idx * 3 + 1], x2 = xs[idx * 3 + 2];
        float d0 = dvs[idx * 3 + 0], d1 = dvs[idx * 3 + 1], d2 = dvs[idx * 3 + 2];

        {
            float ev[16];
#pragma unroll
            for (int i = 0; i < 16; i++) {
                int k = g4 * 16 + i;
                float v;
                if (k < 3) v = (k == 0) ? x0 : ((k == 1) ? x1 : x2);
                else if (k < 63) {
                    int q = k - 3, j = q / 6, r = q % 6, a = r % 3;
                    float xx = (a == 0) ? x0 : ((a == 1) ? x1 : x2);
                    float arg = (float)(1 << j) * xx;
                    v = (r < 3) ? __sinf(arg) : __cosf(arg);
                } else v = 0.0f;
                ev[i] = v;
            }
            uint4 u0, u1;
            u0.x = packrn(ev[0], ev[1]);  u0.y = packrn(ev[2], ev[3]);
            u0.z = packrn(ev[4], ev[5]);  u0.w = packrn(ev[6], ev[7]);
            u1.x = packrn(ev[8], ev[9]);  u1.y = packrn(ev[10], ev[11]);
            u1.z = packrn(ev[12], ev[13]); u1.w = packrn(ev[14], ev[15]);
            int sw = (cidx & 7) << 4;
            *(uint4*)(actA + ((cidx * 128 + g4 * 32) ^ sw)) = u0;
            *(uint4*)(actA + ((cidx * 128 + g4 * 32 + 16) ^ sw)) = u1;
        }
        {
            float ev[8];
#pragma unroll
            for (int i = 0; i < 8; i++) {
                int k = g4 * 8 + i;
                float v;
                if (k < 3) v = (k == 0) ? d0 : ((k == 1) ? d1 : d2);
                else if (k < 27) {
                    int q = k - 3, j = q / 6, r = q % 6, a = r % 3;
                    float xx = (a == 0) ? d0 : ((a == 1) ? d1 : d2);
                    float arg = (float)(1 << j) * xx;
                    v = (r < 3) ? __sinf(arg) : __cosf(arg);
                } else v = 0.0f;
                ev[i] = v;
            }
            uint4 u;
            u.x = packrn(ev[0], ev[1]); u.y = packrn(ev[2], ev[3]);
            u.z = packrn(ev[4], ev[5]); u.w = packrn(ev[6], ev[7]);
            *(uint4*)(actB + ((cidx * 128 + 64 + g4 * 16) ^ ((cidx & 7) << 4))) = u;
        }

        // L1
        {
            f16x8 a0 = ldA(actA, lane, 0);
            f16x8 a1 = ldA(actA, lane, 1);
#pragma unroll
            for (int n = 0; n < 2; n++) {
                float bv = biasc[0 + 16 * n + cidx];
                f32x4 acc = {bv, bv, bv, bv};
                acc = MFMA16(a0, ldB(wBc, 0, n * 2 + 0, lane), acc);
                acc = MFMA16(a1, ldB(wBc, 0, n * 2 + 1, lane), acc);
                stD(actB, 16 * n + cidx, acc, true, g4);
            }
        }
        // L2
        {
            f16x8 a2 = ldA(actB, lane, 0);
#pragma unroll
            for (int n = 0; n < 3; n++) {
                float bv = biasc[32 + 16 * n + cidx];
                f32x4 acc = {bv, bv, bv, bv};
                acc = MFMA16(a2, ldB(wBc, 4096, n, lane), acc);
                int C = 16 * n + cidx;
                if (C == 0) {
#pragma unroll
                    for (int r = 0; r < 4; r++) sigw[g4 * 4 + r] = fmaxf(acc[r], 0.0f);
                } else if (C <= 32) {
                    stD(actA, C - 1, acc, true, g4);
                }
            }
        }
        // L3
        {
            f16x8 a3 = ldA(actA, lane, 0);
#pragma unroll
            for (int n = 0; n < 2; n++) {
                float bv = biasc[80 + 16 * n + cidx];
                f32x4 acc = {bv, bv, bv, bv};
                acc = MFMA16(a3, ldB(wBc, 7168, n, lane), acc);
                stD(actB, 16 * n + cidx, acc, false, g4);
            }
        }
        // L4
        {
            f16x8 a4a = ldA(actB, lane, 0);
            f16x8 a4b = ldA(actB, lane, 1);
#pragma unroll
            for (int n = 0; n < 2; n++) {
                float bv = biasc[112 + 16 * n + cidx];
                f32x4 acc = {bv, bv, bv, bv};
                acc = MFMA16(a4a, ldB(wBc, 9216, n * 2 + 0, lane), acc);
                acc = MFMA16(a4b, ldB(wBc, 9216, n * 2 + 1, lane), acc);
                stD(actA, 16 * n + cidx, acc, true, g4);
            }
        }
        // L5
        {
            f16x8 a5 = ldA(actA, lane, 0);
            float bv = biasc[144 + cidx];
            f32x4 acc = {bv, bv, bv, bv};
            acc = MFMA16(a5, ldB(wBc, 13312, 0, lane), acc);
            if (cidx < 3) {
#pragma unroll
                for (int r = 0; r < 4; r++) {
                    int p = g4 * 4 + r;
                    if (p < nv) out[(size_t)idxw[p] * 3 + cidx] = 1.0f / (1.0f + __expf(-acc[r]));
                }
            } else if (cidx == 3) {
#pragma unroll
                for (int r = 0; r < 4; r++) {
                    int p = g4 * 4 + r;
                    if (p < nv) out[(size_t)3 * P + idxw[p]] = sigw[p];
                }
            }
        }
    }
}

// 4 consecutive cells per block, double-buffered weight staging: cell i+1's
// loads are issued before cell i's MLP and packed into the other LDS buffer
// after it -- HBM latency hides under compute.
__global__ void __launch_bounds__(256) k_mlp(
    const float* __restrict__ xs, const float* __restrict__ dvs,
    const float* __restrict__ w1g, const float* __restrict__ b1g,
    const float* __restrict__ w2g, const float* __restrict__ b2g,
    const float* __restrict__ w3g, const float* __restrict__ b3g,
    const float* __restrict__ w4g, const float* __restrict__ b4g,
    const float* __restrict__ w5g, const float* __restrict__ b5g,
    const int* __restrict__ offsets, const int* __restrict__ sorted,
    float* __restrict__ out, int P) {
    __shared__ __align__(16) char wB[2][14336];
    __shared__ __align__(16) char smem_act[16384];
    __shared__ float bias[2][160];
    __shared__ float sig[64];
    __shared__ int idxL[64];

    int cell0 = blockIdx.x * CPB;
    if (offsets[cell0] == offsets[cell0 + CPB]) return;  // whole block empty (uniform)
    int tid = threadIdx.x;
    int lane = tid & 63;
    int wid = tid >> 6;

    char* actA = smem_act + (wid << 11);
    char* actB = smem_act + 8192 + (wid << 11);
    float* sigw = sig + (wid << 4);
    int* idxw = idxL + (wid << 4);

    // prologue: stage cell0 -> buf 0
    {
        float va[14], vb[14], bvv;
        ph1_all(va, vb, bvv, cell0, tid, w1g, b1g, w2g, b2g, w3g, b3g, w4g, b4g, w5g, b5g);
        ph2_all(wB[0], bias[0], va, vb, bvv, tid);
    }
    __syncthreads();

#pragma unroll
    for (int i = 0; i < CPB; i++) {
        int cur = i & 1;
        int cell = cell0 + i;
        float va[14], vb[14], bvv = 0.0f;
        if (i < CPB - 1) {
            ph1_all(va, vb, bvv, cell + 1, tid, w1g, b1g, w2g, b2g, w3g, b3g, w4g, b4g, w5g, b5g);
        }
        int start = offsets[cell], end = offsets[cell + 1];
        if (start < end) {
            mlp_cell(wB[cur], bias[cur], actA, actB, sigw, idxw, start, end, wid, lane,
                     xs, dvs, sorted, out, P);
        }
        if (i < CPB - 1) {
            ph2_all(wB[cur ^ 1], bias[cur ^ 1], va, vb, bvv, tid);
        }
        __syncthreads();
    }
}

extern "C" void kernel_launch(void* const* d_in, const int* in_sizes, int n_in,
                              void* d_out, int out_size, void* d_ws, size_t ws_size,
                              hipStream_t stream) {
    const float* xs = (const float*)d_in[0];
    const float* dv = (const float*)d_in[1];
    const float* w1 = (const float*)d_in[2];
    const float* b1 = (const float*)d_in[3];
    const float* w2 = (const float*)d_in[4];
    const float* b2 = (const float*)d_in[5];
    const float* w3 = (const float*)d_in[6];
    const float* b3 = (const float*)d_in[7];
    const float* w4 = (const float*)d_in[8];
    const float* b4 = (const float*)d_in[9];
    const float* w5 = (const float*)d_in[10];
    const float* b5 = (const float*)d_in[11];
    float* out = (float*)d_out;
    int P = in_sizes[0] / 3;

    int* counts = (int*)d_ws;
    int* offsets = counts + 4096;
    int* cursor = offsets + 4104;
    int* sorted = cursor + 4096;

    hipMemsetAsync(counts, 0, 4096 * sizeof(int), stream);

    int blk = 256;
    int grd = (P + blk - 1) / blk;
    k_count<<<grd, blk, 0, stream>>>(xs, counts, out, P);
    k_scan<<<1, 64, 0, stream>>>(counts, offsets, cursor);
    k_scatter<<<grd, blk, 0, stream>>>(xs, cursor, sorted, P);
    k_mlp<<<NCELL / CPB, 256, 0, stream>>>(xs, dv, w1, b1, w2, b2, w3, b3, w4, b4, w5, b5,
                                           offsets, sorted, out, P);
}